// Round 5
// baseline (363.315 us; speedup 1.0000x reference)
//
#include <hip/hip_runtime.h>

typedef int   int4v   __attribute__((ext_vector_type(4)));
typedef float float4v __attribute__((ext_vector_type(4)));

#define T_TOK 16384
#define HD    1024
#define IE    256
#define EN    8
#define VSZ   100000

// meta[] int indices
#define M_OFF 16   // [9] group offsets
#define M_TS1 25   // [9] gemm tile-start prefix (Mtile=32)

// ws byte offsets (all 16-aligned)
#define XQ_OFF   0ull           // T*1024 int8 (token-ordered)
#define PB1_OFF  21053440ull    // 8*64*512*16 int8 (gate|up packed)
#define PB2_OFF  25247744ull    // 8*16*1024*16 int8 (down packed)
#define PERM_OFF 27344896ull    // T int32
#define XS_OFF   27410688ull    // T float (token-ordered)
#define META_OFF 27542272ull    // 64 int32
#define BC_OFF   27542528ull    // 64*8 int32 per-block histograms
#define BB_OFF   27544576ull    // 64*8 int32 per-block bases
#define TICK_OFF 27546624ull    // 1 int32 work ticket

// async global->LDS, 16B per lane; LDS dest = wave-uniform base + lane*16
__device__ __forceinline__ void gload16(const void* g, void* l) {
    __builtin_amdgcn_global_load_lds(
        (const __attribute__((address_space(1))) unsigned int*)g,
        (__attribute__((address_space(3))) unsigned int*)l,
        16, 0, 0);
}

// LDS-only barrier: does NOT drain vmcnt (keeps async stages in flight)
#define LDS_BAR() do { \
    asm volatile("s_waitcnt lgkmcnt(0)" ::: "memory"); \
    __builtin_amdgcn_s_barrier(); \
    __builtin_amdgcn_sched_barrier(0); \
} while (0)

// per-block histogram -> bc[block][e]  (no global atomics); also zeroes ticket
__global__ void k_hist(const int* __restrict__ ids, const int* __restrict__ t2e,
                       int* __restrict__ bc, int* __restrict__ tick) {
    __shared__ int h[EN];
    if (threadIdx.x < EN) h[threadIdx.x] = 0;
    if (blockIdx.x == 0 && threadIdx.x == 0) tick[0] = 0;
    __syncthreads();
    int t = blockIdx.x * 256 + threadIdx.x;
    int id = ids[t]; id = min(max(id, 0), VSZ - 1);
    atomicAdd(&h[t2e[id]], 1);
    __syncthreads();
    if (threadIdx.x < EN) bc[blockIdx.x * EN + threadIdx.x] = h[threadIdx.x];
}

// single block, 8 waves (one per expert): prefix over 64 blocks via shuffles
__global__ __launch_bounds__(512) void k_scan(const int* __restrict__ bc,
                                              int* __restrict__ bbase,
                                              int* __restrict__ meta) {
    int e = threadIdx.x >> 6;
    int b = threadIdx.x & 63;
    int c = bc[b * EN + e];
    int inc = c;
    #pragma unroll
    for (int s = 1; s < 64; s <<= 1) {
        int v = __shfl_up(inc, s, 64);
        if (b >= s) inc += v;
    }
    int exc = inc - c;
    __shared__ int tot[EN];
    __shared__ int goff[EN];
    if (b == 63) tot[e] = inc;
    __syncthreads();
    if (threadIdx.x == 0) {
        int off = 0, t1 = 0;
        meta[M_OFF] = 0; meta[M_TS1] = 0;
        #pragma unroll
        for (int i = 0; i < EN; ++i) {
            goff[i] = off;
            int cc = tot[i];
            off += cc; t1 += (cc + 31) >> 5;
            meta[M_OFF + i + 1] = off;
            meta[M_TS1 + i + 1] = t1;
        }
    }
    __syncthreads();
    bbase[b * EN + e] = goff[e] + exc;
}

// LDS cursors seeded from bbase -> zero global atomics
__global__ void k_assign(const int* __restrict__ ids, const int* __restrict__ t2e,
                         const int* __restrict__ bbase, int* __restrict__ perm) {
    __shared__ int cur[EN];
    if (threadIdx.x < EN) cur[threadIdx.x] = bbase[blockIdx.x * EN + threadIdx.x];
    __syncthreads();
    int t = blockIdx.x * 256 + threadIdx.x;
    int id = ids[t]; id = min(max(id, 0), VSZ - 1);
    int e = t2e[id];
    int slot = atomicAdd(&cur[e], 1);
    perm[slot] = t;
}

// ---------------------------------------------------------------------------
// k_pre: token-ordered activation quantization (blocks 0..4095, wave per token)
//        + weight repack into MFMA fragment layout (blocks 4096..5631).
// Fragment layout: elem(k,n) at ((k>>4)*N + n)*16 + (k&15)
// ---------------------------------------------------------------------------
__global__ __launch_bounds__(256) void k_pre(const float* __restrict__ hidden,
                                             const int* __restrict__ gq,
                                             const int* __restrict__ uq,
                                             const int* __restrict__ dq,
                                             signed char* __restrict__ xq,
                                             float* __restrict__ xs,
                                             signed char* __restrict__ pb1,
                                             signed char* __restrict__ pb2) {
    int b = blockIdx.x;
    if (b < 4096) {
        int w = threadIdx.x >> 6, lane = threadIdx.x & 63;
        int token = (b << 2) + w;
        const float* row = hidden + (size_t)token * HD;
        float v[16];
        #pragma unroll
        for (int j = 0; j < 4; ++j) {
            float4v f = *(const float4v*)(row + lane * 16 + j * 4);
            v[j*4+0] = f[0]; v[j*4+1] = f[1]; v[j*4+2] = f[2]; v[j*4+3] = f[3];
        }
        float mx = 0.0f;
        #pragma unroll
        for (int j = 0; j < 16; ++j) mx = fmaxf(mx, fabsf(v[j]));
        #pragma unroll
        for (int s = 1; s < 64; s <<= 1) mx = fmaxf(mx, __shfl_xor(mx, s, 64));
        float sc = fmaxf(mx / 127.0f, 1e-8f);
        if (lane == 0) xs[token] = sc;
        int4v pk;
        #pragma unroll
        for (int j = 0; j < 4; ++j) {
            int bb[4];
            #pragma unroll
            for (int u = 0; u < 4; ++u) {
                float t = rintf(v[j*4+u] / sc);           // round-half-even == jnp.round
                t = fminf(fmaxf(t, -128.0f), 127.0f);
                bb[u] = (int)t;
            }
            pk[j] = (bb[0] & 255) | ((bb[1] & 255) << 8) | ((bb[2] & 255) << 16) | (bb[3] << 24);
        }
        *(int4v*)(xq + (size_t)token * HD + lane * 16) = pk;
    } else {
        int idx = (b - 4096) * 256 + threadIdx.x;   // 0 .. 393215
        if (idx < 262144) {                          // gate|up fragments [8][64][512]
            int n = idx & 511, kc = (idx >> 9) & 63, e = idx >> 15;
            const int* src = (n < 256) ? gq + (((size_t)((e << 10) + (kc << 4)) << 8) + n)
                                       : uq + (((size_t)((e << 10) + (kc << 4)) << 8) + (n - 256));
            int4v pk;
            #pragma unroll
            for (int jj = 0; jj < 4; ++jj) {
                int b0 = src[(size_t)(jj * 4 + 0) << 8], b1 = src[(size_t)(jj * 4 + 1) << 8];
                int b2 = src[(size_t)(jj * 4 + 2) << 8], b3 = src[(size_t)(jj * 4 + 3) << 8];
                pk[jj] = (b0 & 255) | ((b1 & 255) << 8) | ((b2 & 255) << 16) | (b3 << 24);
            }
            *(int4v*)(pb1 + ((size_t)((((e << 6) + kc) << 9) + n) << 4)) = pk;
        } else {                                     // down fragments [8][16][1024]
            int j = idx - 262144;
            int n = j & 1023, kc = (j >> 10) & 15, e = j >> 14;
            const int* src = dq + (((size_t)((e << 8) + (kc << 4)) << 10) + n);
            int4v pk;
            #pragma unroll
            for (int jj = 0; jj < 4; ++jj) {
                int b0 = src[(size_t)(jj * 4 + 0) << 10], b1 = src[(size_t)(jj * 4 + 1) << 10];
                int b2 = src[(size_t)(jj * 4 + 2) << 10], b3 = src[(size_t)(jj * 4 + 3) << 10];
                pk[jj] = (b0 & 255) | ((b1 & 255) << 8) | ((b2 & 255) << 16) | (b3 << 24);
            }
            *(int4v*)(pb2 + ((size_t)((((e << 4) + kc) << 10) + n) << 4)) = pk;
        }
    }
}

// ---------------------------------------------------------------------------
// k_mlp: persistent Mtile=32 fused MLP, 2 blocks/CU, counted-vmcnt 2-buffer
// pipeline. Stages: 16 G1 (gate|up, 8 B-gloads + 2 A-reg-loads = 10 vmem) +
// 8 G2 (down, 8 gloads). Per step:
//   wait vmcnt(size(next stage))  [never 0 until last step]
//   s_barrier                     [everyone's stage-t visible]
//   compute stage t
//   s_barrier                     [read-done -> buffer free]
//   issue stage t+2 into lB[t&1]
// A operands come straight from xq into registers (16B/lane), parity-buffered.
// LDS: lB 2x32KB + iqt 8KB + aux ~0.8KB = 74.5KB -> 2 blocks/CU.
// Work distribution: global ticket -> near-perfect load balance + chip-wide
// expert temporal locality (each XCD's L2 holds the current expert weights).
// ---------------------------------------------------------------------------
__global__ __launch_bounds__(256, 2) void k_mlp(const signed char* __restrict__ xq,
                                                const signed char* __restrict__ pb1,
                                                const signed char* __restrict__ pb2,
                                                const float* __restrict__ xs,
                                                const float* __restrict__ gsc,
                                                const float* __restrict__ usc,
                                                const float* __restrict__ dsc,
                                                const int* __restrict__ meta,
                                                const int* __restrict__ perm,
                                                int* tick,
                                                float* __restrict__ out) {
    const int w = threadIdx.x >> 6, lane = threadIdx.x & 63;
    const int q = lane >> 4, r = lane & 15;

    __shared__ __align__(16) signed char lB[2][32768];
    __shared__ __align__(16) signed char iqt[8192];   // 32x256 swizzled int8
    __shared__ float pmax[128];                        // [4][32]
    __shared__ float rsc[32];
    __shared__ int   ptok[32];
    __shared__ int   s_tile;

    int mts[9], moff[9];
    #pragma unroll
    for (int i = 0; i < 9; ++i) { mts[i] = meta[M_TS1 + i]; moff[i] = meta[M_OFF + i]; }
    const int nt = mts[8];

    for (;;) {
        if (threadIdx.x == 0) s_tile = atomicAdd(tick, 1);
        __syncthreads();
        int tile = s_tile;
        if (tile >= nt) break;

        int e = 0;
        #pragma unroll
        for (int i = 1; i < 8; ++i) if (tile >= mts[i]) e = i;
        int m0 = moff[e] + ((tile - mts[e]) << 5);
        int gend = moff[e + 1];

        if (threadIdx.x < 32) ptok[threadIdx.x] = perm[min(m0 + (int)threadIdx.x, T_TOK - 1)];
        __syncthreads();

        int tokr[2][4];
        #pragma unroll
        for (int mi = 0; mi < 2; ++mi)
            #pragma unroll
            for (int g = 0; g < 4; ++g)
                tokr[mi][g] = ptok[(mi << 4) + (q << 2) + g];
        const signed char* aptr0 = xq + (size_t)ptok[r] * HD + (q << 4);
        const signed char* aptr1 = xq + (size_t)ptok[16 + r] * HD + (q << 4);

        const signed char* pbe1 = pb1 + (size_t)e * (64 * 512 * 16);
        const signed char* pbe2 = pb2 + (size_t)e * (16 * 1024 * 16);

        // hoist all scalar loads above the pipeline (vmcnt arithmetic stays exact;
        // anything outstanding here is older than stage 0 and drains at the first wait)
        float gs[4], us[4];
        #pragma unroll
        for (int i = 0; i < 4; ++i) {
            int n = (w << 6) + (i << 4) + r;
            gs[i] = gsc[e * IE + n];
            us[i] = usc[e * IE + n];
        }
        float xsr[2][4];
        #pragma unroll
        for (int mi = 0; mi < 2; ++mi)
            #pragma unroll
            for (int g = 0; g < 4; ++g)
                xsr[mi][g] = xs[tokr[mi][g]];
        float ds16[2][8];
        #pragma unroll
        for (int nh = 0; nh < 2; ++nh)
            #pragma unroll
            for (int i = 0; i < 8; ++i)
                ds16[nh][i] = dsc[e * HD + (nh << 9) + (w << 7) + (i << 4) + r];

        #define G1B(buf, kt)                                                           \
            {                                                                          \
                int kc0 = (kt) << 2;                                                   \
                _Pragma("unroll")                                                      \
                for (int j = 0; j < 8; ++j) {                                          \
                    int n = ((j << 6) + lane) ^ ((w & 1) << 3);                        \
                    gload16(pbe1 + (((size_t)(kc0 + w) * 512 + n) << 4),               \
                            &lB[buf][((w << 3) + j) << 10]);                           \
                }                                                                      \
            }
        #define G2B(buf, st2)                                                          \
            {                                                                          \
                int kc0 = ((st2) & 3) << 2; int nhs = (st2) >> 2;                      \
                _Pragma("unroll")                                                      \
                for (int j = 0; j < 8; ++j) {                                          \
                    int n = ((j << 6) + lane) ^ ((w & 1) << 3);                        \
                    gload16(pbe2 + (((size_t)(kc0 + w) * 1024 + (nhs << 9) + n) << 4), \
                            &lB[buf][((w << 3) + j) << 10]);                           \
                }                                                                      \
            }

        int4v zero = {0, 0, 0, 0};
        int4v accg[2][4], accu[2][4];
        #pragma unroll
        for (int mi = 0; mi < 2; ++mi)
            #pragma unroll
            for (int i = 0; i < 4; ++i) { accg[mi][i] = zero; accu[mi][i] = zero; }

        int4v areg[2][2];
        // prologue: stages 0 and 1 in flight (10 vmem each: 8 B-gloads + 2 A-loads)
        G1B(0, 0);
        areg[0][0] = *(const int4v*)(aptr0);
        areg[0][1] = *(const int4v*)(aptr1);
        G1B(1, 1);
        areg[1][0] = *(const int4v*)(aptr0 + 64);
        areg[1][1] = *(const int4v*)(aptr1 + 64);

        // ---------------- phase 1: gate|up GEMM, stages 0..15 ----------------
        #pragma unroll
        for (int kt = 0; kt < 16; ++kt) {
            if (kt < 15) { asm volatile("s_waitcnt vmcnt(10) lgkmcnt(0)" ::: "memory"); }
            else         { asm volatile("s_waitcnt vmcnt(8) lgkmcnt(0)" ::: "memory"); }
            __builtin_amdgcn_sched_barrier(0);
            __builtin_amdgcn_s_barrier();      // everyone's stage kt visible
            __builtin_amdgcn_sched_barrier(0);
            const int cur = kt & 1;
            int4v a0 = areg[cur][0], a1 = areg[cur][1];
            #pragma unroll
            for (int i = 0; i < 4; ++i) {
                int n = (w << 6) + (i << 4) + r;
                int sg = (q << 9) + (n ^ ((q & 1) << 3));
                int su = (q << 9) + ((n + 256) ^ ((q & 1) << 3));
                int4v bg = *(const int4v*)&lB[cur][sg << 4];
                int4v bu = *(const int4v*)&lB[cur][su << 4];
                accg[0][i] = __builtin_amdgcn_mfma_i32_16x16x64_i8(a0, bg, accg[0][i], 0, 0, 0);
                accg[1][i] = __builtin_amdgcn_mfma_i32_16x16x64_i8(a1, bg, accg[1][i], 0, 0, 0);
                accu[0][i] = __builtin_amdgcn_mfma_i32_16x16x64_i8(a0, bu, accu[0][i], 0, 0, 0);
                accu[1][i] = __builtin_amdgcn_mfma_i32_16x16x64_i8(a1, bu, accu[1][i], 0, 0, 0);
            }
            __builtin_amdgcn_s_barrier();      // read-done: lB[cur] free
            __builtin_amdgcn_sched_barrier(0);
            if (kt < 14) {
                G1B(cur, kt + 2);
                areg[cur][0] = *(const int4v*)(aptr0 + ((kt + 2) << 6));
                areg[cur][1] = *(const int4v*)(aptr1 + ((kt + 2) << 6));
            } else if (kt == 14) { G2B(0, 0); }
            else                 { G2B(1, 1); }
        }
        #undef G1B

        // ------- epilogue: silu*up, row max, requant (lgkm-only barriers;
        //         down-weight stages 16/17 stay in flight) -------
        float inter[2][4][4];
        float pm[2][4];
        #pragma unroll
        for (int mi = 0; mi < 2; ++mi)
            #pragma unroll
            for (int g = 0; g < 4; ++g) {
                float mx = 0.0f;
                #pragma unroll
                for (int i = 0; i < 4; ++i) {
                    float gv = (float)accg[mi][i][g] * xsr[mi][g] * gs[i];
                    float uv = (float)accu[mi][i][g] * xsr[mi][g] * us[i];
                    float sg = gv / (1.0f + expf(-gv));
                    float vv = sg * uv;
                    inter[mi][i][g] = vv;
                    mx = fmaxf(mx, fabsf(vv));
                }
                #pragma unroll
                for (int s = 1; s < 16; s <<= 1) mx = fmaxf(mx, __shfl_xor(mx, s, 64));
                pm[mi][g] = mx;
            }

        if (r == 0) {
            #pragma unroll
            for (int mi = 0; mi < 2; ++mi)
                #pragma unroll
                for (int g = 0; g < 4; ++g)
                    pmax[(w << 5) + (mi << 4) + (q << 2) + g] = pm[mi][g];
        }
        LDS_BAR();
        if (threadIdx.x < 32) {
            int row = threadIdx.x;
            float mx = fmaxf(fmaxf(pmax[row], pmax[32 + row]), fmaxf(pmax[64 + row], pmax[96 + row]));
            rsc[row] = fmaxf(mx / 127.0f, 1e-8f);
        }
        LDS_BAR();
        float rscr[2][4];
        #pragma unroll
        for (int mi = 0; mi < 2; ++mi)
            #pragma unroll
            for (int g = 0; g < 4; ++g)
                rscr[mi][g] = rsc[(mi << 4) + (q << 2) + g];

        // quantize inter -> swizzled iqt tile (separate LDS array, no overlay)
        #pragma unroll
        for (int mi = 0; mi < 2; ++mi)
            #pragma unroll
            for (int g = 0; g < 4; ++g) {
                int row = (mi << 4) + (q << 2) + g;
                float sc = rscr[mi][g];
                #pragma unroll
                for (int i = 0; i < 4; ++i) {
                    float t = rintf(inter[mi][i][g] / sc);
                    t = fminf(fmaxf(t, -128.0f), 127.0f);
                    iqt[(row << 8) + ((((w << 2) + i) ^ (row & 3)) << 4) + r] = (signed char)(int)t;
                }
            }
        LDS_BAR();   // iqt published

        // ---------------- phase 3: down GEMM, stages 16..23 ----------------
        int4v acc2[2][8];
        #pragma unroll
        for (int st = 0; st < 8; ++st) {     // st = nh*4 + kt2
            if (st < 7) { asm volatile("s_waitcnt vmcnt(8) lgkmcnt(0)" ::: "memory"); }
            else        { asm volatile("s_waitcnt vmcnt(0) lgkmcnt(0)" ::: "memory"); }
            __builtin_amdgcn_sched_barrier(0);
            __builtin_amdgcn_s_barrier();
            __builtin_amdgcn_sched_barrier(0);
            if ((st & 3) == 0) {
                #pragma unroll
                for (int mi = 0; mi < 2; ++mi)
                    #pragma unroll
                    for (int i = 0; i < 8; ++i) acc2[mi][i] = zero;
            }
            const int cur = st & 1;
            int4v a2[2];
            #pragma unroll
            for (int mi = 0; mi < 2; ++mi) {
                int row2 = (mi << 4) + r;
                a2[mi] = *(const int4v*)&iqt[(row2 << 8) + (((((st & 3) << 2) + q) ^ (r & 3)) << 4)];
            }
            #pragma unroll
            for (int i = 0; i < 8; ++i) {
                int n = (w << 7) + (i << 4) + r;
                int sb = (q << 9) + (n ^ ((q & 1) << 3));
                int4v bb = *(const int4v*)&lB[cur][sb << 4];
                acc2[0][i] = __builtin_amdgcn_mfma_i32_16x16x64_i8(a2[0], bb, acc2[0][i], 0, 0, 0);
                acc2[1][i] = __builtin_amdgcn_mfma_i32_16x16x64_i8(a2[1], bb, acc2[1][i], 0, 0, 0);
            }
            if ((st & 3) == 3) {
                int nhs = st >> 2;
                #pragma unroll
                for (int mi = 0; mi < 2; ++mi)
                    #pragma unroll
                    for (int g = 0; g < 4; ++g) {
                        int slot = m0 + (mi << 4) + (q << 2) + g;
                        if (slot < gend) {
                            size_t ob = (size_t)tokr[mi][g] * HD + (nhs << 9) + (w << 7) + r;
                            #pragma unroll
                            for (int i = 0; i < 8; ++i)
                                out[ob + (i << 4)] = (float)acc2[mi][i][g] * rscr[mi][g] * ds16[nhs][i];
                        }
                    }
            }
            __builtin_amdgcn_s_barrier();      // read-done: lB[cur] free
            __builtin_amdgcn_sched_barrier(0);
            if (st < 6) { G2B(cur, st + 2); }
        }
        #undef G2B

        __syncthreads();   // tile boundary: full drain before s_tile rewrite / lB reuse
    }
}

extern "C" void kernel_launch(void* const* d_in, const int* in_sizes, int n_in,
                              void* d_out, int out_size, void* d_ws, size_t ws_size,
                              hipStream_t stream) {
    const float* hidden = (const float*)d_in[0];
    const int*   ids    = (const int*)d_in[1];
    const int*   gq     = (const int*)d_in[2];
    const float* gsc    = (const float*)d_in[3];
    const int*   uq     = (const int*)d_in[4];
    const float* usc    = (const float*)d_in[5];
    const int*   dq     = (const int*)d_in[6];
    const float* dsc    = (const float*)d_in[7];
    const int*   t2e    = (const int*)d_in[8];
    float* out = (float*)d_out;

    char* ws = (char*)d_ws;
    signed char* xq  = (signed char*)(ws + XQ_OFF);
    signed char* pb1 = (signed char*)(ws + PB1_OFF);
    signed char* pb2 = (signed char*)(ws + PB2_OFF);
    int*   perm = (int*)(ws + PERM_OFF);
    float* xs   = (float*)(ws + XS_OFF);
    int*   meta = (int*)(ws + META_OFF);
    int*   bc   = (int*)(ws + BC_OFF);
    int*   bbase= (int*)(ws + BB_OFF);
    int*   tick = (int*)(ws + TICK_OFF);

    k_hist<<<64, 256, 0, stream>>>(ids, t2e, bc, tick);
    k_scan<<<1, 512, 0, stream>>>(bc, bbase, meta);
    k_assign<<<64, 256, 0, stream>>>(ids, t2e, bbase, perm);
    k_pre<<<5632, 256, 0, stream>>>(hidden, gq, uq, dq, xq, xs, pb1, pb2);
    k_mlp<<<512, 256, 0, stream>>>(xq, pb1, pb2, xs, gsc, usc, dsc, meta, perm, tick, out);
}

// Round 6
// 210.143 us; speedup vs baseline: 1.7289x; 1.7289x over previous
//
#include <hip/hip_runtime.h>

typedef int   int4v   __attribute__((ext_vector_type(4)));
typedef float float4v __attribute__((ext_vector_type(4)));

#define T_TOK 16384
#define HD    1024
#define IE    256
#define EN    8
#define VSZ   100000

// meta[] int indices
#define M_OFF 16   // [9] group offsets
#define M_TS1 25   // [9] gemm tile-start prefix (Mtile=32)

// ws byte offsets (all 16-aligned)
#define XQ_OFF   0ull           // T*1024 int8 (token-ordered)
#define PB1_OFF  21053440ull    // 8*64*512*16 int8 (gate|up packed)
#define PB2_OFF  25247744ull    // 8*16*1024*16 int8 (down packed)
#define PERM_OFF 27344896ull    // T int32
#define XS_OFF   27410688ull    // T float (token-ordered)
#define META_OFF 27542272ull    // 64 int32
#define BC_OFF   27542528ull    // 64*8 int32 per-block histograms
#define BB_OFF   27544576ull    // 64*8 int32 per-block bases

// async global->LDS, 16B per lane; LDS dest = wave-uniform base + lane*16
__device__ __forceinline__ void gload16(const void* g, void* l) {
    __builtin_amdgcn_global_load_lds(
        (const __attribute__((address_space(1))) unsigned int*)g,
        (__attribute__((address_space(3))) unsigned int*)l,
        16, 0, 0);
}

// LDS-only barrier: does NOT drain vmcnt (keeps async stages in flight)
#define LDS_BAR() do { \
    asm volatile("s_waitcnt lgkmcnt(0)" ::: "memory"); \
    __builtin_amdgcn_s_barrier(); \
    __builtin_amdgcn_sched_barrier(0); \
} while (0)

// per-block histogram -> bc[block][e]  (no global atomics)
__global__ void k_hist(const int* __restrict__ ids, const int* __restrict__ t2e,
                       int* __restrict__ bc) {
    __shared__ int h[EN];
    if (threadIdx.x < EN) h[threadIdx.x] = 0;
    __syncthreads();
    int t = blockIdx.x * 256 + threadIdx.x;
    int id = ids[t]; id = min(max(id, 0), VSZ - 1);
    atomicAdd(&h[t2e[id]], 1);
    __syncthreads();
    if (threadIdx.x < EN) bc[blockIdx.x * EN + threadIdx.x] = h[threadIdx.x];
}

// single block, 8 waves (one per expert): prefix over 64 blocks via shuffles
__global__ __launch_bounds__(512) void k_scan(const int* __restrict__ bc,
                                              int* __restrict__ bbase,
                                              int* __restrict__ meta) {
    int e = threadIdx.x >> 6;
    int b = threadIdx.x & 63;
    int c = bc[b * EN + e];
    int inc = c;
    #pragma unroll
    for (int s = 1; s < 64; s <<= 1) {
        int v = __shfl_up(inc, s, 64);
        if (b >= s) inc += v;
    }
    int exc = inc - c;
    __shared__ int tot[EN];
    __shared__ int goff[EN];
    if (b == 63) tot[e] = inc;
    __syncthreads();
    if (threadIdx.x == 0) {
        int off = 0, t1 = 0;
        meta[M_OFF] = 0; meta[M_TS1] = 0;
        #pragma unroll
        for (int i = 0; i < EN; ++i) {
            goff[i] = off;
            int cc = tot[i];
            off += cc; t1 += (cc + 31) >> 5;
            meta[M_OFF + i + 1] = off;
            meta[M_TS1 + i + 1] = t1;
        }
    }
    __syncthreads();
    bbase[b * EN + e] = goff[e] + exc;
}

// LDS cursors seeded from bbase -> zero global atomics
__global__ void k_assign(const int* __restrict__ ids, const int* __restrict__ t2e,
                         const int* __restrict__ bbase, int* __restrict__ perm) {
    __shared__ int cur[EN];
    if (threadIdx.x < EN) cur[threadIdx.x] = bbase[blockIdx.x * EN + threadIdx.x];
    __syncthreads();
    int t = blockIdx.x * 256 + threadIdx.x;
    int id = ids[t]; id = min(max(id, 0), VSZ - 1);
    int e = t2e[id];
    int slot = atomicAdd(&cur[e], 1);
    perm[slot] = t;
}

// ---------------------------------------------------------------------------
// k_pre: token-ordered activation quantization (blocks 0..4095, wave per token)
//        + weight repack into MFMA fragment layout (blocks 4096..5631).
// Fragment layout: elem(k,n) at ((k>>4)*N + n)*16 + (k&15)
// ---------------------------------------------------------------------------
__global__ __launch_bounds__(256) void k_pre(const float* __restrict__ hidden,
                                             const int* __restrict__ gq,
                                             const int* __restrict__ uq,
                                             const int* __restrict__ dq,
                                             signed char* __restrict__ xq,
                                             float* __restrict__ xs,
                                             signed char* __restrict__ pb1,
                                             signed char* __restrict__ pb2) {
    int b = blockIdx.x;
    if (b < 4096) {
        int w = threadIdx.x >> 6, lane = threadIdx.x & 63;
        int token = (b << 2) + w;
        const float* row = hidden + (size_t)token * HD;
        float v[16];
        #pragma unroll
        for (int j = 0; j < 4; ++j) {
            float4v f = *(const float4v*)(row + lane * 16 + j * 4);
            v[j*4+0] = f[0]; v[j*4+1] = f[1]; v[j*4+2] = f[2]; v[j*4+3] = f[3];
        }
        float mx = 0.0f;
        #pragma unroll
        for (int j = 0; j < 16; ++j) mx = fmaxf(mx, fabsf(v[j]));
        #pragma unroll
        for (int s = 1; s < 64; s <<= 1) mx = fmaxf(mx, __shfl_xor(mx, s, 64));
        float sc = fmaxf(mx / 127.0f, 1e-8f);
        if (lane == 0) xs[token] = sc;
        int4v pk;
        #pragma unroll
        for (int j = 0; j < 4; ++j) {
            int bb[4];
            #pragma unroll
            for (int u = 0; u < 4; ++u) {
                float t = rintf(v[j*4+u] / sc);           // round-half-even == jnp.round
                t = fminf(fmaxf(t, -128.0f), 127.0f);
                bb[u] = (int)t;
            }
            pk[j] = (bb[0] & 255) | ((bb[1] & 255) << 8) | ((bb[2] & 255) << 16) | (bb[3] << 24);
        }
        *(int4v*)(xq + (size_t)token * HD + lane * 16) = pk;
    } else {
        int idx = (b - 4096) * 256 + threadIdx.x;   // 0 .. 393215
        if (idx < 262144) {                          // gate|up fragments [8][64][512]
            int n = idx & 511, kc = (idx >> 9) & 63, e = idx >> 15;
            const int* src = (n < 256) ? gq + (((size_t)((e << 10) + (kc << 4)) << 8) + n)
                                       : uq + (((size_t)((e << 10) + (kc << 4)) << 8) + (n - 256));
            int4v pk;
            #pragma unroll
            for (int jj = 0; jj < 4; ++jj) {
                int b0 = src[(size_t)(jj * 4 + 0) << 8], b1 = src[(size_t)(jj * 4 + 1) << 8];
                int b2 = src[(size_t)(jj * 4 + 2) << 8], b3 = src[(size_t)(jj * 4 + 3) << 8];
                pk[jj] = (b0 & 255) | ((b1 & 255) << 8) | ((b2 & 255) << 16) | (b3 << 24);
            }
            *(int4v*)(pb1 + ((size_t)((((e << 6) + kc) << 9) + n) << 4)) = pk;
        } else {                                     // down fragments [8][16][1024]
            int j = idx - 262144;
            int n = j & 1023, kc = (j >> 10) & 15, e = j >> 14;
            const int* src = dq + (((size_t)((e << 8) + (kc << 4)) << 10) + n);
            int4v pk;
            #pragma unroll
            for (int jj = 0; jj < 4; ++jj) {
                int b0 = src[(size_t)(jj * 4 + 0) << 10], b1 = src[(size_t)(jj * 4 + 1) << 10];
                int b2 = src[(size_t)(jj * 4 + 2) << 10], b3 = src[(size_t)(jj * 4 + 3) << 10];
                pk[jj] = (b0 & 255) | ((b1 & 255) << 8) | ((b2 & 255) << 16) | (b3 << 24);
            }
            *(int4v*)(pb2 + ((size_t)((((e << 4) + kc) << 10) + n) << 4)) = pk;
        }
    }
}

// ---------------------------------------------------------------------------
// k_mlp: Mtile=32 fused MLP, STATIC XCD-swizzled tile map (round-2 locality)
// + counted-vmcnt 2-buffer pipeline (round-5 schedule).
// Stages: 16 G1 (8 B-gloads + 2 A-reg-loads = 10 vmem) + 8 G2 (8 gloads).
// Per step:
//   wait vmcnt(size(next stage))   [never 0 until last step]
//   s_barrier                      [everyone's stage-t visible]
//   compute stage t
//   s_barrier                      [read-done -> buffer free]
//   issue stage t+2 into lB[t&1]
// A operands load straight from xq into registers, parity-buffered.
// LDS: lB 2x32KB + iqt 8KB + aux ~0.8KB = 74.5KB -> 2 blocks/CU.
// Tile map: tile = (blk%8)*65 + blk/8 (520 = 8*65, bijective) -> 65
// consecutive same-expert tiles per XCD -> weights stay L2-resident.
// ---------------------------------------------------------------------------
__global__ __launch_bounds__(256, 2) void k_mlp(const signed char* __restrict__ xq,
                                                const signed char* __restrict__ pb1,
                                                const signed char* __restrict__ pb2,
                                                const float* __restrict__ xs,
                                                const float* __restrict__ gsc,
                                                const float* __restrict__ usc,
                                                const float* __restrict__ dsc,
                                                const int* __restrict__ meta,
                                                const int* __restrict__ perm,
                                                float* __restrict__ out) {
    int b = (blockIdx.x & 7) * 65 + (blockIdx.x >> 3);   // XCD-contiguous tiles
    int e = -1, m0 = 0, gend = 0;
    #pragma unroll
    for (int i = 0; i < EN; ++i) {
        int s0 = meta[M_TS1 + i], s1 = meta[M_TS1 + i + 1];
        if (b >= s0 && b < s1) { e = i; m0 = meta[M_OFF + i] + ((b - s0) << 5); gend = meta[M_OFF + i + 1]; }
    }
    if (e < 0) return;   // block-uniform exit
    const int w = threadIdx.x >> 6, lane = threadIdx.x & 63;
    const int q = lane >> 4, r = lane & 15;

    __shared__ __align__(16) signed char lB[2][32768];
    __shared__ __align__(16) signed char iqt[8192];   // 32x256 swizzled int8
    __shared__ float pmax[128];                        // [4][32]
    __shared__ float rsc[32];
    __shared__ int   ptok[32];

    if (threadIdx.x < 32) ptok[threadIdx.x] = perm[min(m0 + (int)threadIdx.x, T_TOK - 1)];
    __syncthreads();

    int tokr[2][4];
    #pragma unroll
    for (int mi = 0; mi < 2; ++mi)
        #pragma unroll
        for (int g = 0; g < 4; ++g)
            tokr[mi][g] = ptok[(mi << 4) + (q << 2) + g];
    const signed char* aptr0 = xq + (size_t)ptok[r] * HD + (q << 4);
    const signed char* aptr1 = xq + (size_t)ptok[16 + r] * HD + (q << 4);

    const signed char* pbe1 = pb1 + (size_t)e * (64 * 512 * 16);
    const signed char* pbe2 = pb2 + (size_t)e * (16 * 1024 * 16);

    // hoist all scalar loads above the pipeline; anything outstanding here is
    // older than stage 0 and drains at the first counted wait
    float gs[4], us[4];
    #pragma unroll
    for (int i = 0; i < 4; ++i) {
        int n = (w << 6) + (i << 4) + r;
        gs[i] = gsc[e * IE + n];
        us[i] = usc[e * IE + n];
    }
    float xsr[2][4];
    #pragma unroll
    for (int mi = 0; mi < 2; ++mi)
        #pragma unroll
        for (int g = 0; g < 4; ++g)
            xsr[mi][g] = xs[tokr[mi][g]];
    float ds16[2][8];
    #pragma unroll
    for (int nh = 0; nh < 2; ++nh)
        #pragma unroll
        for (int i = 0; i < 8; ++i)
            ds16[nh][i] = dsc[e * HD + (nh << 9) + (w << 7) + (i << 4) + r];

    #define G1B(buf, kt)                                                           \
        {                                                                          \
            int kc0 = (kt) << 2;                                                   \
            _Pragma("unroll")                                                      \
            for (int j = 0; j < 8; ++j) {                                          \
                int n = ((j << 6) + lane) ^ ((w & 1) << 3);                        \
                gload16(pbe1 + (((size_t)(kc0 + w) * 512 + n) << 4),               \
                        &lB[buf][((w << 3) + j) << 10]);                           \
            }                                                                      \
        }
    #define G2B(buf, st2)                                                          \
        {                                                                          \
            int kc0 = ((st2) & 3) << 2; int nhs = (st2) >> 2;                      \
            _Pragma("unroll")                                                      \
            for (int j = 0; j < 8; ++j) {                                          \
                int n = ((j << 6) + lane) ^ ((w & 1) << 3);                        \
                gload16(pbe2 + (((size_t)(kc0 + w) * 1024 + (nhs << 9) + n) << 4), \
                        &lB[buf][((w << 3) + j) << 10]);                           \
            }                                                                      \
        }

    int4v zero = {0, 0, 0, 0};
    int4v accg[2][4], accu[2][4];
    #pragma unroll
    for (int mi = 0; mi < 2; ++mi)
        #pragma unroll
        for (int i = 0; i < 4; ++i) { accg[mi][i] = zero; accu[mi][i] = zero; }

    int4v areg[2][2];
    // prologue: stages 0 and 1 in flight (10 vmem each: 8 B-gloads + 2 A-loads)
    G1B(0, 0);
    areg[0][0] = *(const int4v*)(aptr0);
    areg[0][1] = *(const int4v*)(aptr1);
    G1B(1, 1);
    areg[1][0] = *(const int4v*)(aptr0 + 64);
    areg[1][1] = *(const int4v*)(aptr1 + 64);

    // ---------------- phase 1: gate|up GEMM, stages 0..15 ----------------
    #pragma unroll
    for (int kt = 0; kt < 16; ++kt) {
        if (kt < 15) { asm volatile("s_waitcnt vmcnt(10) lgkmcnt(0)" ::: "memory"); }
        else         { asm volatile("s_waitcnt vmcnt(8) lgkmcnt(0)" ::: "memory"); }
        __builtin_amdgcn_sched_barrier(0);
        __builtin_amdgcn_s_barrier();      // everyone's stage kt visible
        __builtin_amdgcn_sched_barrier(0);
        const int cur = kt & 1;
        int4v a0 = areg[cur][0], a1 = areg[cur][1];
        #pragma unroll
        for (int i = 0; i < 4; ++i) {
            int n = (w << 6) + (i << 4) + r;
            int sg = (q << 9) + (n ^ ((q & 1) << 3));
            int su = (q << 9) + ((n + 256) ^ ((q & 1) << 3));
            int4v bg = *(const int4v*)&lB[cur][sg << 4];
            int4v bu = *(const int4v*)&lB[cur][su << 4];
            accg[0][i] = __builtin_amdgcn_mfma_i32_16x16x64_i8(a0, bg, accg[0][i], 0, 0, 0);
            accg[1][i] = __builtin_amdgcn_mfma_i32_16x16x64_i8(a1, bg, accg[1][i], 0, 0, 0);
            accu[0][i] = __builtin_amdgcn_mfma_i32_16x16x64_i8(a0, bu, accu[0][i], 0, 0, 0);
            accu[1][i] = __builtin_amdgcn_mfma_i32_16x16x64_i8(a1, bu, accu[1][i], 0, 0, 0);
        }
        __builtin_amdgcn_s_barrier();      // read-done: lB[cur] free
        __builtin_amdgcn_sched_barrier(0);
        if (kt < 14) {
            G1B(cur, kt + 2);
            areg[cur][0] = *(const int4v*)(aptr0 + ((kt + 2) << 6));
            areg[cur][1] = *(const int4v*)(aptr1 + ((kt + 2) << 6));
        } else if (kt == 14) { G2B(0, 0); }
        else                 { G2B(1, 1); }
    }
    #undef G1B

    // ------- epilogue: silu*up, row max, requant (lgkm-only barriers;
    //         down-weight stages 16/17 stay in flight) -------
    float inter[2][4][4];
    float pm[2][4];
    #pragma unroll
    for (int mi = 0; mi < 2; ++mi)
        #pragma unroll
        for (int g = 0; g < 4; ++g) {
            float mx = 0.0f;
            #pragma unroll
            for (int i = 0; i < 4; ++i) {
                float gv = (float)accg[mi][i][g] * xsr[mi][g] * gs[i];
                float uv = (float)accu[mi][i][g] * xsr[mi][g] * us[i];
                float sg = gv / (1.0f + expf(-gv));
                float vv = sg * uv;
                inter[mi][i][g] = vv;
                mx = fmaxf(mx, fabsf(vv));
            }
            #pragma unroll
            for (int s = 1; s < 16; s <<= 1) mx = fmaxf(mx, __shfl_xor(mx, s, 64));
            pm[mi][g] = mx;
        }

    if (r == 0) {
        #pragma unroll
        for (int mi = 0; mi < 2; ++mi)
            #pragma unroll
            for (int g = 0; g < 4; ++g)
                pmax[(w << 5) + (mi << 4) + (q << 2) + g] = pm[mi][g];
    }
    LDS_BAR();
    if (threadIdx.x < 32) {
        int row = threadIdx.x;
        float mx = fmaxf(fmaxf(pmax[row], pmax[32 + row]), fmaxf(pmax[64 + row], pmax[96 + row]));
        rsc[row] = fmaxf(mx / 127.0f, 1e-8f);
    }
    LDS_BAR();
    float rscr[2][4];
    #pragma unroll
    for (int mi = 0; mi < 2; ++mi)
        #pragma unroll
        for (int g = 0; g < 4; ++g)
            rscr[mi][g] = rsc[(mi << 4) + (q << 2) + g];

    // quantize inter -> swizzled iqt tile (separate LDS array, no overlay)
    #pragma unroll
    for (int mi = 0; mi < 2; ++mi)
        #pragma unroll
        for (int g = 0; g < 4; ++g) {
            int row = (mi << 4) + (q << 2) + g;
            float sc = rscr[mi][g];
            #pragma unroll
            for (int i = 0; i < 4; ++i) {
                float t = rintf(inter[mi][i][g] / sc);
                t = fminf(fmaxf(t, -128.0f), 127.0f);
                iqt[(row << 8) + ((((w << 2) + i) ^ (row & 3)) << 4) + r] = (signed char)(int)t;
            }
        }
    LDS_BAR();   // iqt published

    // ---------------- phase 3: down GEMM, stages 16..23 ----------------
    int4v acc2[2][8];
    #pragma unroll
    for (int st = 0; st < 8; ++st) {     // st = nh*4 + kt2
        if (st < 7) { asm volatile("s_waitcnt vmcnt(8) lgkmcnt(0)" ::: "memory"); }
        else        { asm volatile("s_waitcnt vmcnt(0) lgkmcnt(0)" ::: "memory"); }
        __builtin_amdgcn_sched_barrier(0);
        __builtin_amdgcn_s_barrier();
        __builtin_amdgcn_sched_barrier(0);
        if ((st & 3) == 0) {
            #pragma unroll
            for (int mi = 0; mi < 2; ++mi)
                #pragma unroll
                for (int i = 0; i < 8; ++i) acc2[mi][i] = zero;
        }
        const int cur = st & 1;
        int4v a2[2];
        #pragma unroll
        for (int mi = 0; mi < 2; ++mi) {
            int row2 = (mi << 4) + r;
            a2[mi] = *(const int4v*)&iqt[(row2 << 8) + (((((st & 3) << 2) + q) ^ (r & 3)) << 4)];
        }
        #pragma unroll
        for (int i = 0; i < 8; ++i) {
            int n = (w << 7) + (i << 4) + r;
            int sb = (q << 9) + (n ^ ((q & 1) << 3));
            int4v bb = *(const int4v*)&lB[cur][sb << 4];
            acc2[0][i] = __builtin_amdgcn_mfma_i32_16x16x64_i8(a2[0], bb, acc2[0][i], 0, 0, 0);
            acc2[1][i] = __builtin_amdgcn_mfma_i32_16x16x64_i8(a2[1], bb, acc2[1][i], 0, 0, 0);
        }
        if ((st & 3) == 3) {
            int nhs = st >> 2;
            #pragma unroll
            for (int mi = 0; mi < 2; ++mi)
                #pragma unroll
                for (int g = 0; g < 4; ++g) {
                    int slot = m0 + (mi << 4) + (q << 2) + g;
                    if (slot < gend) {
                        size_t ob = (size_t)tokr[mi][g] * HD + (nhs << 9) + (w << 7) + r;
                        #pragma unroll
                        for (int i = 0; i < 8; ++i)
                            out[ob + (i << 4)] = (float)acc2[mi][i][g] * rscr[mi][g] * ds16[nhs][i];
                    }
                }
        }
        __builtin_amdgcn_s_barrier();      // read-done: lB[cur] free
        __builtin_amdgcn_sched_barrier(0);
        if (st < 6) { G2B(cur, st + 2); }
    }
    #undef G2B
}

extern "C" void kernel_launch(void* const* d_in, const int* in_sizes, int n_in,
                              void* d_out, int out_size, void* d_ws, size_t ws_size,
                              hipStream_t stream) {
    const float* hidden = (const float*)d_in[0];
    const int*   ids    = (const int*)d_in[1];
    const int*   gq     = (const int*)d_in[2];
    const float* gsc    = (const float*)d_in[3];
    const int*   uq     = (const int*)d_in[4];
    const float* usc    = (const float*)d_in[5];
    const int*   dq     = (const int*)d_in[6];
    const float* dsc    = (const float*)d_in[7];
    const int*   t2e    = (const int*)d_in[8];
    float* out = (float*)d_out;

    char* ws = (char*)d_ws;
    signed char* xq  = (signed char*)(ws + XQ_OFF);
    signed char* pb1 = (signed char*)(ws + PB1_OFF);
    signed char* pb2 = (signed char*)(ws + PB2_OFF);
    int*   perm = (int*)(ws + PERM_OFF);
    float* xs   = (float*)(ws + XS_OFF);
    int*   meta = (int*)(ws + META_OFF);
    int*   bc   = (int*)(ws + BC_OFF);
    int*   bbase= (int*)(ws + BB_OFF);

    k_hist<<<64, 256, 0, stream>>>(ids, t2e, bc);
    k_scan<<<1, 512, 0, stream>>>(bc, bbase, meta);
    k_assign<<<64, 256, 0, stream>>>(ids, t2e, bbase, perm);
    k_pre<<<5632, 256, 0, stream>>>(hidden, gq, uq, dq, xq, xs, pb1, pb2);
    k_mlp<<<520, 256, 0, stream>>>(xq, pb1, pb2, xs, gsc, usc, dsc, meta, perm, out);
}